// Round 14
// baseline (546.496 us; speedup 1.0000x reference)
//
#include <hip/hip_runtime.h>

// features: (16, 64, 65536) f32, coords: (16, 3, 65536) f32, resolution = 32
constexpr int Rr = 32;
constexpr int R2 = Rr * Rr;          // 1024
constexpr int R3 = Rr * Rr * Rr;     // 32768
constexpr int Bb = 16;
constexpr int Cc = 64;
constexpr int Nn = 65536;
constexpr int VOX_ELEMS = Bb * Cc * R3;    // 33,554,432
constexpr int NCELL  = Bb * R3;            // 524,288
constexpr int NSLOTS = Bb * Nn;            // 1,048,576

// RTNE pack of two f32 into one u32 of 2x bf16 (lo = a, hi = b)
__device__ __forceinline__ unsigned pack_bf16(float a, float b)
{
    unsigned ua = __float_as_uint(a);
    unsigned ub = __float_as_uint(b);
    ua += 0x7FFFu + ((ua >> 16) & 1u);
    ub += 0x7FFFu + ((ub >> 16) & 1u);
    return (ua >> 16) | (ub & 0xFFFF0000u);
}

// ---------------- K0: zero cnt (2 MB) ----------------
__global__ __launch_bounds__(256) void zero_cnt_kernel(float4* __restrict__ base)
{
    int i = blockIdx.x * 256 + threadIdx.x;        // NCELL*4/16 elements
    base[i] = float4{0.0f, 0.0f, 0.0f, 0.0f};
}

// ---------------- K1: norm_coords + cell idx + counts ----------------
__global__ __launch_bounds__(256) void vox_coords_kernel(
    const float* __restrict__ coords,
    float* __restrict__ norm_out,
    int* __restrict__ idx_out,
    int* __restrict__ cnt)
{
    int t = blockIdx.x * 256 + threadIdx.x;        // t = b*N + i
    int b = t >> 16;
    int i = t & (Nn - 1);

    const float* cp = coords + (size_t)b * 3 * Nn + i;
    float x = cp[0];
    float y = cp[Nn];
    float z = cp[2 * Nn];

    float nx = fminf(fmaxf((x + 1.0f) * 16.0f, 0.0f), 31.0f);
    float ny = fminf(fmaxf((y + 1.0f) * 16.0f, 0.0f), 31.0f);
    float nz = fminf(fmaxf((z + 1.0f) * 16.0f, 0.0f), 31.0f);

    float* np_ = norm_out + (size_t)b * 3 * Nn + i;
    np_[0]      = nx;
    np_[Nn]     = ny;
    np_[2 * Nn] = nz;

    int idx = (int)rintf(nx) * R2 + (int)rintf(ny) * Rr + (int)rintf(nz);

    idx_out[t] = idx;
    atomicAdd(&cnt[(b << 15) + idx], 1);
}

// ---------------- Scan phase 1: per-block exclusive scan ----------------
__global__ __launch_bounds__(256) void scan1_kernel(
    const int* __restrict__ cnt, int* __restrict__ cursor, int* __restrict__ bsums)
{
    __shared__ int sm[256];
    int t = blockIdx.x * 256 + threadIdx.x;
    int v = cnt[t];
    sm[threadIdx.x] = v;
    __syncthreads();
#pragma unroll
    for (int off = 1; off < 256; off <<= 1) {
        int x = (threadIdx.x >= off) ? sm[threadIdx.x - off] : 0;
        __syncthreads();
        sm[threadIdx.x] += x;
        __syncthreads();
    }
    cursor[t] = sm[threadIdx.x] - v;
    if (threadIdx.x == 255) bsums[blockIdx.x] = sm[255];
}

// ---------------- Scan phase 2 ----------------
__global__ __launch_bounds__(256) void scan2_kernel(int* __restrict__ bsums)
{
    __shared__ int sm[256];
    int carry = 0;
    for (int chunk = 0; chunk < 2048; chunk += 256) {
        int v = bsums[chunk + threadIdx.x];
        sm[threadIdx.x] = v;
        __syncthreads();
#pragma unroll
        for (int off = 1; off < 256; off <<= 1) {
            int x = (threadIdx.x >= off) ? sm[threadIdx.x - off] : 0;
            __syncthreads();
            sm[threadIdx.x] += x;
            __syncthreads();
        }
        bsums[chunk + threadIdx.x] = carry + sm[threadIdx.x] - v;
        carry += sm[255];
        __syncthreads();
    }
}

// ---------------- Scan phase 3 ----------------
__global__ __launch_bounds__(256) void scan3_kernel(
    int* __restrict__ cursor, const int* __restrict__ bsums)
{
    int t = blockIdx.x * 256 + threadIdx.x;
    cursor[t] += bsums[blockIdx.x];
}

// ---------------- Bin: slotbuf[t] = idx on entry, unique slot on exit ----------------
__global__ __launch_bounds__(256) void bin_kernel(
    int* __restrict__ slotbuf, int* __restrict__ cursor)
{
    int t = blockIdx.x * 256 + threadIdx.x;
    int b = t >> 16;
    int idx = slotbuf[t];                                // read cell idx
    int slot = atomicAdd(&cursor[(b << 15) + idx], 1);   // L2-resident 2 MB table
    slotbuf[t] = slot;                                   // overwrite with slot
}
// after this, cursor[cell] == END offset of the cell's slot segment

// ---------------- K3: coalesced read -> LDS transpose -> plain 128B bf16 rows ----------------
__global__ __launch_bounds__(256) void tscatter_kernel(
    const float* __restrict__ feat,
    const int* __restrict__ slotbuf,
    unsigned short* __restrict__ featS)    // bf16 rows, [slot][64ch]
{
    __shared__ float lds[64 * 65];                 // [n][c], stride 65
    __shared__ int   slot_sm[64];
    int b    = blockIdx.x >> 10;
    int tile = blockIdx.x & 1023;
    int n0   = tile << 6;
    int t    = threadIdx.x;

    if (t < 64) slot_sm[t] = slotbuf[(b << 16) + n0 + t];

#pragma unroll
    for (int q = 0; q < 4; ++q) {
        int c  = (t >> 4) + (q << 4);
        int n4 = (t & 15) << 2;
        float4 v = *(const float4*)(feat + (((size_t)(b * Cc + c)) << 16) + n0 + n4);
        lds[(n4 + 0) * 65 + c] = v.x;
        lds[(n4 + 1) * 65 + c] = v.y;
        lds[(n4 + 2) * 65 + c] = v.z;
        lds[(n4 + 3) * 65 + c] = v.w;
    }
    __syncthreads();

    // per wave-instr: lanes 0-31 commit row n, lanes 32-63 row n+1 (128 B bf16 rows)
    int wave = t >> 6, lane = t & 63;
    int hi = lane >> 5;                // 0 or 1
    int m  = lane & 31;                // channel-pair index
#pragma unroll
    for (int kk = 0; kk < 8; ++kk) {
        int n = (wave << 4) + (kk << 1) + hi;
        float f0 = lds[n * 65 + (m << 1) + 0];
        float f1 = lds[n * 65 + (m << 1) + 1];
        *(unsigned*)(featS + ((size_t)slot_sm[n] << 6) + (m << 1)) = pack_bf16(f0, f1);
    }
}

// ---------------- K4: merge cell's rows (predicated 4 + rare tail), f32, transpose ----------------
__global__ __launch_bounds__(256) void merge_transpose_kernel(
    const unsigned short* __restrict__ featS,
    const int* __restrict__ cursor,    // end offsets
    const int* __restrict__ cnt,
    float* __restrict__ vox)
{
    __shared__ float lds[64 * 65];                 // [cell][ch], stride 65
    int b    = blockIdx.x >> 9;
    int tile = blockIdx.x & 511;
    int v0   = tile << 6;
    int t    = threadIdx.x;
    int cl   = t >> 2;                             // cell-local 0..63
    int q    = t & 3;                              // ch group of 16

    int cell  = (b << 15) + v0 + cl;
    int cn    = cnt[cell];
    int start = cursor[cell] - cn;

    const unsigned short* base = featS + ((size_t)start << 6) + (q << 4);

    // first 4 rows: predicated loads issued up front (full MLP)
    uint4 wa[4], wb[4];
#pragma unroll
    for (int k = 0; k < 4; ++k) {
        if (k < cn) {
            wa[k] = *(const uint4*)(base + (k << 6));
            wb[k] = *(const uint4*)(base + (k << 6) + 8);
        } else {
            wa[k] = uint4{0u, 0u, 0u, 0u};
            wb[k] = uint4{0u, 0u, 0u, 0u};
        }
    }

    float acc[16];
#pragma unroll
    for (int j = 0; j < 16; ++j) acc[j] = 0.0f;

#pragma unroll
    for (int k = 0; k < 4; ++k) {
        const unsigned* w = &wa[k].x;
#pragma unroll
        for (int j = 0; j < 4; ++j) {
            acc[2 * j + 0] += __uint_as_float(w[j] << 16);
            acc[2 * j + 1] += __uint_as_float(w[j] & 0xFFFF0000u);
        }
        const unsigned* w2 = &wb[k].x;
#pragma unroll
        for (int j = 0; j < 4; ++j) {
            acc[8 + 2 * j + 0] += __uint_as_float(w2[j] << 16);
            acc[8 + 2 * j + 1] += __uint_as_float(w2[j] & 0xFFFF0000u);
        }
    }

    // rare tail (boundary cells): affine sequential rows
    for (int k = 4; k < cn; ++k) {
        uint4 w0 = *(const uint4*)(base + (k << 6));
        uint4 w1 = *(const uint4*)(base + (k << 6) + 8);
        const unsigned* w = &w0.x;
#pragma unroll
        for (int j = 0; j < 4; ++j) {
            acc[2 * j + 0] += __uint_as_float(w[j] << 16);
            acc[2 * j + 1] += __uint_as_float(w[j] & 0xFFFF0000u);
        }
        const unsigned* w2 = &w1.x;
#pragma unroll
        for (int j = 0; j < 4; ++j) {
            acc[8 + 2 * j + 0] += __uint_as_float(w2[j] << 16);
            acc[8 + 2 * j + 1] += __uint_as_float(w2[j] & 0xFFFF0000u);
        }
    }

    float inv = cn ? 1.0f / (float)cn : 0.0f;      // empty cell -> 0 (== 0/1e-5)
#pragma unroll
    for (int j = 0; j < 16; ++j)
        lds[cl * 65 + (q << 4) + j] = acc[j] * inv;
    __syncthreads();

    int wave = t >> 6, lane = t & 63;
#pragma unroll
    for (int k = 0; k < 16; ++k) {
        int c = (wave << 4) + k;
        vox[(((size_t)(b * Cc + c)) << 15) + v0 + lane] = lds[lane * 65 + c];
    }
}

extern "C" void kernel_launch(void* const* d_in, const int* in_sizes, int n_in,
                              void* d_out, int out_size, void* d_ws, size_t ws_size,
                              hipStream_t stream)
{
    const float* features = (const float*)d_in[0];
    const float* coords   = (const float*)d_in[1];

    float* out      = (float*)d_out;
    float* vox      = out;
    float* norm_out = out + VOX_ELEMS;

    // ws layout: cnt 2MB | cursor 2MB | slotbuf 4MB | bsums 8KB | featS bf16 134MB (+pad)
    char* ws = (char*)d_ws;
    int*            cnt     = (int*)ws;            ws += (size_t)NCELL * 4;
    int*            cursor  = (int*)ws;            ws += (size_t)NCELL * 4;
    int*            slotbuf = (int*)ws;            ws += (size_t)NSLOTS * 4;
    int*            bsums   = (int*)ws;            ws += 2048 * 4;
    unsigned short* featS   = (unsigned short*)ws; // (NSLOTS+64) rows of 128 B

    zero_cnt_kernel<<<NCELL * 4 / 16 / 256, 256, 0, stream>>>((float4*)cnt);
    vox_coords_kernel<<<(Bb * Nn) / 256, 256, 0, stream>>>(coords, norm_out, slotbuf, cnt);
    scan1_kernel<<<NCELL / 256, 256, 0, stream>>>(cnt, cursor, bsums);
    scan2_kernel<<<1, 256, 0, stream>>>(bsums);
    scan3_kernel<<<NCELL / 256, 256, 0, stream>>>(cursor, bsums);
    bin_kernel<<<(Bb * Nn) / 256, 256, 0, stream>>>(slotbuf, cursor);
    tscatter_kernel<<<Bb * 1024, 256, 0, stream>>>(features, slotbuf, featS);
    merge_transpose_kernel<<<Bb * 512, 256, 0, stream>>>(featS, cursor, cnt, vox);
}

// Round 15
// 234.588 us; speedup vs baseline: 2.3296x; 2.3296x over previous
//
#include <hip/hip_runtime.h>

// features: (16, 64, 65536) f32, coords: (16, 3, 65536) f32, resolution = 32
constexpr int Rr = 32;
constexpr int R2 = Rr * Rr;          // 1024
constexpr int R3 = Rr * Rr * Rr;     // 32768
constexpr int Bb = 16;
constexpr int Cc = 64;
constexpr int Nn = 65536;
constexpr int VOX_ELEMS = Bb * Cc * R3;    // 33,554,432
constexpr int NCELL = Bb * R3;             // 524,288

// RTNE pack of two f32 into one u32 of 2x bf16 (lo = a, hi = b)
__device__ __forceinline__ unsigned pack_bf16(float a, float b)
{
    unsigned ua = __float_as_uint(a);
    unsigned ub = __float_as_uint(b);
    ua += 0x7FFFu + ((ua >> 16) & 1u);
    ub += 0x7FFFu + ((ub >> 16) & 1u);
    return (ua >> 16) | (ub & 0xFFFF0000u);
}

// ---------------- K0: zero cnt (2 MB) ----------------
__global__ __launch_bounds__(256) void zero_cnt_kernel(float4* __restrict__ base)
{
    int i = blockIdx.x * 256 + threadIdx.x;        // NCELL*4/16 elements
    base[i] = float4{0.0f, 0.0f, 0.0f, 0.0f};
}

// ---------------- K1: norm_coords + cell + within-cell rank (clamped to 7) ----------------
__global__ __launch_bounds__(256) void vox_coords_kernel(
    const float* __restrict__ coords,
    float* __restrict__ norm_out,
    int* __restrict__ idx_out,
    int* __restrict__ cnt)
{
    int t = blockIdx.x * 256 + threadIdx.x;        // t = b*N + i
    int b = t >> 16;
    int i = t & (Nn - 1);

    const float* cp = coords + (size_t)b * 3 * Nn + i;
    float x = cp[0];
    float y = cp[Nn];
    float z = cp[2 * Nn];

    float nx = fminf(fmaxf((x + 1.0f) * 16.0f, 0.0f), 31.0f);
    float ny = fminf(fmaxf((y + 1.0f) * 16.0f, 0.0f), 31.0f);
    float nz = fminf(fmaxf((z + 1.0f) * 16.0f, 0.0f), 31.0f);

    float* np_ = norm_out + (size_t)b * 3 * Nn + i;
    np_[0]      = nx;
    np_[Nn]     = ny;
    np_[2 * Nn] = nz;

    int idx = (int)rintf(nx) * R2 + (int)rintf(ny) * Rr + (int)rintf(nz);

    int k = atomicAdd(&cnt[(b << 15) + idx], 1);   // within-cell rank
    idx_out[t] = (idx << 3) | min(k, 7);           // 15b cell | 3b clamped rank
}

// ---------------- K2: pre-zero last-slot rows of overflow cells (cnt > S) ----------------
template <int S>
__global__ __launch_bounds__(256) void slotzero_kernel(
    const int* __restrict__ cnt, unsigned short* __restrict__ voxS)
{
    int g = blockIdx.x * 256 + threadIdx.x;        // NCELL*8 threads
    int cell = g >> 3;
    int p    = g & 7;
    if (cnt[cell] > S)                             // 2MB table, L2-resident
        *(float4*)(voxS + (size_t)cell * (S * 64) + (S - 1) * 64 + (p << 3)) =
            float4{0.0f, 0.0f, 0.0f, 0.0f};        // 8 ushorts = 16 B
}

// ---------------- K3: coalesced read -> LDS transpose -> slotted 128B row stores ----------------
template <int S>
__global__ __launch_bounds__(256) void tscatter_store_kernel(
    const float* __restrict__ feat,
    const int* __restrict__ idx_ws,
    const int* __restrict__ cnt,
    unsigned short* __restrict__ voxS)     // bf16, [cell][slot0..S-1][64ch]
{
    __shared__ float lds[64 * 65];                 // [n][c], stride 65
    __shared__ int   dest_sm[64];                  // ushort offset of the point's row
    __shared__ int   at_sm[64];                    // 1 = use atomic (overflow)
    int b    = blockIdx.x >> 10;
    int tile = blockIdx.x & 1023;
    int n0   = tile << 6;
    int t    = threadIdx.x;

    if (t < 64) {
        int e    = idx_ws[(b << 16) + n0 + t];
        int cell = (b << 15) + (e >> 3);
        int k    = e & 7;                          // clamped rank
        int cn   = cnt[cell];                      // final count, L2-hot
        dest_sm[t] = cell * (S * 64) + min(k, S - 1) * 64;   // ushort units
        at_sm[t]   = (k >= S - 1 && cn > S) ? 1 : 0;
    }

#pragma unroll
    for (int q = 0; q < 4; ++q) {
        int c  = (t >> 4) + (q << 4);
        int n4 = (t & 15) << 2;
        float4 v = *(const float4*)(feat + (((size_t)(b * Cc + c)) << 16) + n0 + n4);
        lds[(n4 + 0) * 65 + c] = v.x;
        lds[(n4 + 1) * 65 + c] = v.y;
        lds[(n4 + 2) * 65 + c] = v.z;
        lds[(n4 + 3) * 65 + c] = v.w;
    }
    __syncthreads();

    // per wave-instr: lanes 0-31 commit row n, lanes 32-63 row n+1 (128 B bf16 rows)
    int wave = t >> 6, lane = t & 63;
    int hi = lane >> 5;                // 0 or 1
    int m  = lane & 31;                // channel-pair index
#pragma unroll
    for (int kk = 0; kk < 8; ++kk) {
        int n = (wave << 4) + (kk << 1) + hi;
        float f0 = lds[n * 65 + (m << 1) + 0];
        float f1 = lds[n * 65 + (m << 1) + 1];
        unsigned pk = pack_bf16(f0, f1);
        unsigned short* addr = voxS + (size_t)dest_sm[n] + (m << 1);
        if (at_sm[n]) {
            asm volatile("global_atomic_pk_add_bf16 %0, %1, off"
                         :: "v"(addr), "v"(pk) : "memory");
        } else {
            *(unsigned*)addr = pk;                 // plain 4 B store, full-line rows
        }
    }
}

// ---------------- K4: merge S slots (fixed unroll, predicated loads, f32) + transpose ----------------
template <int S>
__global__ __launch_bounds__(256) void merge_transpose_kernel(
    const unsigned short* __restrict__ voxS,
    const int* __restrict__ cnt,
    float* __restrict__ vox)
{
    __shared__ float lds[64 * 65];                 // [cell][ch], stride 65
    int b    = blockIdx.x >> 9;
    int tile = blockIdx.x & 511;
    int v0   = tile << 6;
    int t    = threadIdx.x;
    int cl   = t >> 2;                             // cell-local 0..63
    int q    = t & 3;                              // ch group of 16

    int cell = (b << 15) + v0 + cl;
    int cn   = cnt[cell];

    const unsigned short* base = voxS + (size_t)cell * (S * 64) + (q << 4);

    // All (predicated) loads issued up front -> one waitcnt, full MLP.
    uint4 wa[S], wb[S];
#pragma unroll
    for (int k = 0; k < S; ++k) {
        if (k < cn) {
            wa[k] = *(const uint4*)(base + (k << 6));
            wb[k] = *(const uint4*)(base + (k << 6) + 8);
        } else {
            wa[k] = uint4{0u, 0u, 0u, 0u};
            wb[k] = uint4{0u, 0u, 0u, 0u};
        }
    }

    float acc[16];
#pragma unroll
    for (int j = 0; j < 16; ++j) acc[j] = 0.0f;

#pragma unroll
    for (int k = 0; k < S; ++k) {
        const unsigned* w = &wa[k].x;
#pragma unroll
        for (int j = 0; j < 4; ++j) {
            acc[2 * j + 0] += __uint_as_float(w[j] << 16);
            acc[2 * j + 1] += __uint_as_float(w[j] & 0xFFFF0000u);
        }
        const unsigned* w2 = &wb[k].x;
#pragma unroll
        for (int j = 0; j < 4; ++j) {
            acc[8 + 2 * j + 0] += __uint_as_float(w2[j] << 16);
            acc[8 + 2 * j + 1] += __uint_as_float(w2[j] & 0xFFFF0000u);
        }
    }

    float inv = cn ? 1.0f / (float)cn : 0.0f;      // empty cell -> 0 (== 0/1e-5)
#pragma unroll
    for (int j = 0; j < 16; ++j)
        lds[cl * 65 + (q << 4) + j] = acc[j] * inv;
    __syncthreads();

    int wave = t >> 6, lane = t & 63;
#pragma unroll
    for (int k = 0; k < 16; ++k) {
        int c = (wave << 4) + k;
        vox[(((size_t)(b * Cc + c)) << 15) + v0 + lane] = lds[lane * 65 + c];
    }
}

extern "C" void kernel_launch(void* const* d_in, const int* in_sizes, int n_in,
                              void* d_out, int out_size, void* d_ws, size_t ws_size,
                              hipStream_t stream)
{
    const float* features = (const float*)d_in[0];
    const float* coords   = (const float*)d_in[1];

    float* out      = (float*)d_out;
    float* vox      = out;
    float* norm_out = out + VOX_ELEMS;

    // ws layout: cnt (2MB) | idx (4MB) | voxS bf16 S-slot (S=8: 536MB, S=4: 268MB; NOT zeroed)
    char* ws = (char*)d_ws;
    int*            cnt    = (int*)ws;            ws += (size_t)NCELL * 4;
    int*            idx_ws = (int*)ws;            ws += (size_t)Bb * Nn * 4;
    unsigned short* voxS   = (unsigned short*)ws;

    size_t fixed = (size_t)NCELL * 4 + (size_t)Bb * Nn * 4;
    bool use8 = ws_size >= fixed + (size_t)NCELL * 8 * 64 * 2;   // 536 MB slot array

    zero_cnt_kernel<<<NCELL * 4 / 16 / 256, 256, 0, stream>>>((float4*)cnt);
    vox_coords_kernel<<<(Bb * Nn) / 256, 256, 0, stream>>>(coords, norm_out, idx_ws, cnt);

    if (use8) {
        slotzero_kernel<8><<<NCELL * 8 / 256, 256, 0, stream>>>(cnt, voxS);
        tscatter_store_kernel<8><<<Bb * 1024, 256, 0, stream>>>(features, idx_ws, cnt, voxS);
        merge_transpose_kernel<8><<<Bb * 512, 256, 0, stream>>>(voxS, cnt, vox);
    } else {
        slotzero_kernel<4><<<NCELL * 8 / 256, 256, 0, stream>>>(cnt, voxS);
        tscatter_store_kernel<4><<<Bb * 1024, 256, 0, stream>>>(features, idx_ws, cnt, voxS);
        merge_transpose_kernel<4><<<Bb * 512, 256, 0, stream>>>(voxS, cnt, vox);
    }
}

// Round 16
// 225.152 us; speedup vs baseline: 2.4272x; 1.0419x over previous
//
#include <hip/hip_runtime.h>

// features: (16, 64, 65536) f32, coords: (16, 3, 65536) f32, resolution = 32
constexpr int Rr = 32;
constexpr int R2 = Rr * Rr;          // 1024
constexpr int R3 = Rr * Rr * Rr;     // 32768
constexpr int Bb = 16;
constexpr int Cc = 64;
constexpr int Nn = 65536;
constexpr int VOX_ELEMS = Bb * Cc * R3;    // 33,554,432
constexpr int NCELL = Bb * R3;             // 524,288

// RTNE pack of two f32 into one u32 of 2x bf16 (lo = a, hi = b)
__device__ __forceinline__ unsigned pack_bf16(float a, float b)
{
    unsigned ua = __float_as_uint(a);
    unsigned ub = __float_as_uint(b);
    ua += 0x7FFFu + ((ua >> 16) & 1u);
    ub += 0x7FFFu + ((ub >> 16) & 1u);
    return (ua >> 16) | (ub & 0xFFFF0000u);
}

// ---------------- K0: zero cnt (2 MB) ----------------
__global__ __launch_bounds__(256) void zero_cnt_kernel(float4* __restrict__ base)
{
    int i = blockIdx.x * 256 + threadIdx.x;        // NCELL*4/16 elements
    base[i] = float4{0.0f, 0.0f, 0.0f, 0.0f};
}

// ---------------- K1: norm_coords + cell + within-cell rank k ----------------
__global__ __launch_bounds__(256) void vox_coords_kernel(
    const float* __restrict__ coords,
    float* __restrict__ norm_out,
    int* __restrict__ idx_out,
    int* __restrict__ cnt)
{
    int t = blockIdx.x * 256 + threadIdx.x;        // t = b*N + i
    int b = t >> 16;
    int i = t & (Nn - 1);

    const float* cp = coords + (size_t)b * 3 * Nn + i;
    float x = cp[0];
    float y = cp[Nn];
    float z = cp[2 * Nn];

    float nx = fminf(fmaxf((x + 1.0f) * 16.0f, 0.0f), 31.0f);
    float ny = fminf(fmaxf((y + 1.0f) * 16.0f, 0.0f), 31.0f);
    float nz = fminf(fmaxf((z + 1.0f) * 16.0f, 0.0f), 31.0f);

    float* np_ = norm_out + (size_t)b * 3 * Nn + i;
    np_[0]      = nx;
    np_[Nn]     = ny;
    np_[2 * Nn] = nz;

    int idx = (int)rintf(nx) * R2 + (int)rintf(ny) * Rr + (int)rintf(nz);

    int k = atomicAdd(&cnt[(b << 15) + idx], 1);   // within-cell rank
    idx_out[t] = (idx << 3) | min(k, 7);           // 15b cell | 3b clamped rank
}

// ---------------- K2: pre-zero slot3 rows of overflow cells (cnt>4) ----------------
__global__ __launch_bounds__(256) void slot3zero_kernel(
    const int* __restrict__ cnt, unsigned short* __restrict__ voxT4)
{
    int g = blockIdx.x * 256 + threadIdx.x;        // NCELL*8 threads
    int cell = g >> 3;
    int p    = g & 7;
    if (cnt[cell] > 4)                             // 2MB table, L2-resident
        *(float4*)(voxT4 + ((size_t)cell << 8) + 192 + (p << 3)) =
            float4{0.0f, 0.0f, 0.0f, 0.0f};        // 8 ushorts = 16 B
}

// ---------------- K3: coalesced read -> LDS transpose -> slotted 128B row stores ----------------
__global__ __launch_bounds__(256) void tscatter_store_kernel(
    const float* __restrict__ feat,
    const int* __restrict__ idx_ws,
    const int* __restrict__ cnt,
    unsigned short* __restrict__ voxT4)    // bf16, [cell][slot0..3][64ch]
{
    __shared__ float lds[64 * 65];                 // [n][c], stride 65
    __shared__ int   dest_sm[64];                  // ushort offset of the point's row
    __shared__ int   at_sm[64];                    // 1 = use atomic (overflow)
    int b    = blockIdx.x >> 10;
    int tile = blockIdx.x & 1023;
    int n0   = tile << 6;
    int t    = threadIdx.x;

    if (t < 64) {
        int e    = idx_ws[(b << 16) + n0 + t];
        int cell = (b << 15) + (e >> 3);
        int k    = e & 7;                          // clamped rank
        int cn   = cnt[cell];                      // final count, L2-hot
        dest_sm[t] = (cell << 8) + (min(k, 3) << 6);   // ushort units
        at_sm[t]   = (k >= 3 && cn > 4) ? 1 : 0;
    }

#pragma unroll
    for (int q = 0; q < 4; ++q) {
        int c  = (t >> 4) + (q << 4);
        int n4 = (t & 15) << 2;
        float4 v = *(const float4*)(feat + (((size_t)(b * Cc + c)) << 16) + n0 + n4);
        lds[(n4 + 0) * 65 + c] = v.x;
        lds[(n4 + 1) * 65 + c] = v.y;
        lds[(n4 + 2) * 65 + c] = v.z;
        lds[(n4 + 3) * 65 + c] = v.w;
    }
    __syncthreads();

    // per wave-instr: lanes 0-31 commit row n, lanes 32-63 row n+1 (128 B bf16 rows)
    int wave = t >> 6, lane = t & 63;
    int hi = lane >> 5;                // 0 or 1
    int m  = lane & 31;                // channel-pair index
#pragma unroll
    for (int kk = 0; kk < 8; ++kk) {
        int n = (wave << 4) + (kk << 1) + hi;
        float f0 = lds[n * 65 + (m << 1) + 0];
        float f1 = lds[n * 65 + (m << 1) + 1];
        unsigned pk = pack_bf16(f0, f1);
        unsigned short* addr = voxT4 + (size_t)dest_sm[n] + (m << 1);
        if (at_sm[n]) {
            asm volatile("global_atomic_pk_add_bf16 %0, %1, off"
                         :: "v"(addr), "v"(pk) : "memory");
        } else {
            *(unsigned*)addr = pk;                 // plain 4 B store, full-line rows
        }
    }
}

// ---------------- K4: merge slots (masked, f32) + divide + transpose to vox ----------------
__global__ __launch_bounds__(256) void merge_transpose_kernel(
    const unsigned short* __restrict__ voxT4,
    const int* __restrict__ cnt,
    float* __restrict__ vox)
{
    __shared__ float lds[64 * 65];                 // [cell][ch], stride 65
    int b    = blockIdx.x >> 9;
    int tile = blockIdx.x & 511;
    int v0   = tile << 6;
    int t    = threadIdx.x;
    int cl   = t >> 2;                             // cell-local 0..63
    int q    = t & 3;                              // ch group of 16

    int cell = (b << 15) + v0 + cl;
    int cn   = cnt[cell];
    int kmax = min(cn, 4);

    float acc[16];
#pragma unroll
    for (int j = 0; j < 16; ++j) acc[j] = 0.0f;

    const unsigned short* base = voxT4 + ((size_t)cell << 8) + (q << 4);
    for (int k = 0; k < kmax; ++k) {
        // 16 ch = 32 B = two uint4 loads
        uint4 w0 = *(const uint4*)(base + (k << 6));
        uint4 w1 = *(const uint4*)(base + (k << 6) + 8);
        const unsigned* w = &w0.x;
#pragma unroll
        for (int j = 0; j < 4; ++j) {
            acc[2 * j + 0] += __uint_as_float(w[j] << 16);
            acc[2 * j + 1] += __uint_as_float(w[j] & 0xFFFF0000u);
        }
        const unsigned* w2 = &w1.x;
#pragma unroll
        for (int j = 0; j < 4; ++j) {
            acc[8 + 2 * j + 0] += __uint_as_float(w2[j] << 16);
            acc[8 + 2 * j + 1] += __uint_as_float(w2[j] & 0xFFFF0000u);
        }
    }

    float inv = cn ? 1.0f / (float)cn : 0.0f;      // empty cell -> 0 (== 0/1e-5)
#pragma unroll
    for (int j = 0; j < 16; ++j)
        lds[cl * 65 + (q << 4) + j] = acc[j] * inv;
    __syncthreads();

    int wave = t >> 6, lane = t & 63;
#pragma unroll
    for (int k = 0; k < 16; ++k) {
        int c = (wave << 4) + k;
        vox[(((size_t)(b * Cc + c)) << 15) + v0 + lane] = lds[lane * 65 + c];
    }
}

extern "C" void kernel_launch(void* const* d_in, const int* in_sizes, int n_in,
                              void* d_out, int out_size, void* d_ws, size_t ws_size,
                              hipStream_t stream)
{
    const float* features = (const float*)d_in[0];
    const float* coords   = (const float*)d_in[1];

    float* out      = (float*)d_out;
    float* vox      = out;
    float* norm_out = out + VOX_ELEMS;

    // ws layout: cnt (2MB) | idx (4MB) | voxT4 bf16 4-slot (268MB, NOT zeroed)
    char* ws = (char*)d_ws;
    int*            cnt    = (int*)ws;            ws += (size_t)NCELL * 4;
    int*            idx_ws = (int*)ws;            ws += (size_t)Bb * Nn * 4;
    unsigned short* voxT4  = (unsigned short*)ws; // NCELL * 4 slots * 64 ch bf16

    zero_cnt_kernel<<<NCELL * 4 / 16 / 256, 256, 0, stream>>>((float4*)cnt);
    vox_coords_kernel<<<(Bb * Nn) / 256, 256, 0, stream>>>(coords, norm_out, idx_ws, cnt);
    slot3zero_kernel<<<NCELL * 8 / 256, 256, 0, stream>>>(cnt, voxT4);
    tscatter_store_kernel<<<Bb * 1024, 256, 0, stream>>>(features, idx_ws, cnt, voxT4);
    merge_transpose_kernel<<<Bb * 512, 256, 0, stream>>>(voxT4, cnt, vox);
}